// Round 1
// baseline (12564.716 us; speedup 1.0000x reference)
//
#include <hip/hip_runtime.h>
#include <stdint.h>

#define T_   512
#define DIN  128
#define H_   256
#define OUTD 128
#define BB   16   // batch rows per group
#define UU   16   // hidden units per member block

typedef __attribute__((ext_vector_type(8))) short s8v;
typedef __attribute__((ext_vector_type(4))) float f4v;

__device__ __forceinline__ f4v mfma16x16x32(s8v a, s8v b, f4v c) {
  return __builtin_amdgcn_mfma_f32_16x16x32_bf16(a, b, c, 0, 0, 0);
}

// split fp32 into bf16 hi (truncate) + bf16 lo (RN of remainder): f ~= hi + lo with ~2^-17 residual
__device__ __forceinline__ void split_bf16(float f, short &hi, short &lo) {
  unsigned u  = __float_as_uint(f);
  unsigned uh = u & 0xffff0000u;
  hi = (short)(uh >> 16);
  float r = f - __uint_as_float(uh);
  unsigned ur = __float_as_uint(r);
  lo = (short)((ur + 0x7fffu + ((ur >> 16) & 1u)) >> 16);
}

__device__ __forceinline__ unsigned pack_hilo(float f) {
  short hi, lo; split_bf16(f, hi, lo);
  return ((unsigned)(unsigned short)hi << 16) | (unsigned)(unsigned short)lo;
}

__device__ __forceinline__ float sig_(float x) { return 1.f / (1.f + __expf(-x)); }
__device__ __forceinline__ float th_(float x)  { float e = __expf(2.f * x); return 1.f - 2.f / (e + 1.f); }

// One LSTM layer. 256 blocks: group g = batch rows [g*16, g*16+16), member m = hidden units
// [m*16, m*16+16) i.e. gate rows {g4*256 + U0 + u}. Weights live in registers as bf16 hi/lo
// MFMA B-fragments for the whole kernel. Per step: stage x_t + h_{t-1} (bf16 hi/lo) in LDS,
// 3-chain bf16x3 MFMA, gate combine via LDS, state update in registers, h exchange via
// agent-scope atomics + per-(group,step) counter barrier.
template <int KX, bool WRITE_SEQ>
__global__ __launch_bounds__(256, 1) void lstm_layer(
    const float* __restrict__ xin,   // [256, 512, KX]
    const float* __restrict__ Wih,   // [1024, KX]
    const float* __restrict__ Whh,   // [1024, 256]
    const float* __restrict__ bih, const float* __restrict__ bhh,
    float* __restrict__ seq_out,     // WRITE_SEQ ? [256,512,256] : [256,256] (last h)
    unsigned* __restrict__ hbuf,     // [16][2][16*256] packed hi/lo
    unsigned* __restrict__ cnt,      // [16][512], pre-zeroed
    int guard)
{
  constexpr int NKX = KX / 32;       // x-side K fragments
  const int tid  = threadIdx.x;
  const int bid  = blockIdx.x;
  const int g    = (bid & 7) * 2 + ((bid >> 3) & 1);  // XCD-swizzled group id
  const int mem  = bid >> 4;                          // member within group
  const int B0 = g * BB, U0 = mem * UU;
  const int w = tid >> 6;            // wave id == gate id (0=i,1=f,2=g,3=o)
  const int lane = tid & 63;
  const int n = lane & 15, q = lane >> 4;
  const int bb = tid >> 4, uu = tid & 15;             // (batch, unit) for staging/activation

  __shared__ __align__(16) short xhi[BB][KX + 8], xlo[BB][KX + 8];
  __shared__ __align__(16) short hhi[BB][264],    hlo[BB][264];
  __shared__ float gl[4][16][17];
  __shared__ float bias_s[64];
  __shared__ float pad_lds[14000];   // occupancy pad: force 1 block/CU
  if (guard < 0) ((volatile float*)pad_lds)[tid] = 0.f;

  // ---- load weight slice into register fragments (once) ----
  s8v wxh[NKX], wxl[NKX], whhh[8], whhl[8];
  {
    const int row = w * 256 + U0 + n;  // B-frag: lane holds B[k][n] = W[row(n)][k]
    #pragma unroll
    for (int kf = 0; kf < NKX; ++kf) {
      s8v vh, vl;
      #pragma unroll
      for (int j = 0; j < 8; ++j) {
        short hi, lo; split_bf16(Wih[row * KX + kf * 32 + q * 8 + j], hi, lo);
        vh[j] = hi; vl[j] = lo;
      }
      wxh[kf] = vh; wxl[kf] = vl;
    }
    #pragma unroll
    for (int kf = 0; kf < 8; ++kf) {
      s8v vh, vl;
      #pragma unroll
      for (int j = 0; j < 8; ++j) {
        short hi, lo; split_bf16(Whh[row * 256 + kf * 32 + q * 8 + j], hi, lo);
        vh[j] = hi; vl[j] = lo;
      }
      whhh[kf] = vh; whhl[kf] = vl;
    }
  }
  if (tid < 64) {
    int gate = tid >> 4, u = tid & 15;
    int grow = gate * 256 + U0 + u;
    bias_s[tid] = bih[grow] + bhh[grow];
  }

  float c = 0.f;
  unsigned* hb_base = hbuf + (unsigned)g * 2u * 4096u;
  unsigned* cnt_g   = cnt + g * T_;

  for (int t = 0; t < T_; ++t) {
    // ---- global x loads issued BEFORE the spin (overlap with barrier wait) ----
    float xv[KX / 16];
    {
      const float* px = xin + ((size_t)(B0 + bb) * T_ + t) * KX + uu * (KX / 16);
      #pragma unroll
      for (int i = 0; i < KX / 64; ++i) {
        float4 v = *(const float4*)(px + i * 4);
        xv[i * 4 + 0] = v.x; xv[i * 4 + 1] = v.y; xv[i * 4 + 2] = v.z; xv[i * 4 + 3] = v.w;
      }
    }

    if (t > 0) {
      if (tid == 0) {   // leader acquire-spin, with timeout (no-hang safety)
        unsigned it = 0;
        while (__hip_atomic_load(&cnt_g[t - 1], __ATOMIC_ACQUIRE, __HIP_MEMORY_SCOPE_AGENT) < 16u) {
          if (++it > 50000u) break;
          __builtin_amdgcn_s_sleep(1);
        }
      }
      __syncthreads();
      const unsigned* hb = hb_base + ((unsigned)((t - 1) & 1)) * 4096u;
      #pragma unroll
      for (int i = 0; i < 16; ++i) {  // coalesced: lane-consecutive dwords
        unsigned v = __hip_atomic_load(&hb[i * 256 + tid], __ATOMIC_RELAXED, __HIP_MEMORY_SCOPE_AGENT);
        hhi[i][tid] = (short)(v >> 16);
        hlo[i][tid] = (short)(v & 0xffffu);
      }
    } else {
      for (int i = tid; i < BB * 264; i += 256) { (&hhi[0][0])[i] = 0; (&hlo[0][0])[i] = 0; }
    }

    // ---- stage x_t as bf16 hi/lo ----
    #pragma unroll
    for (int i = 0; i < KX / 16; i += 8) {
      s8v vh, vl;
      #pragma unroll
      for (int j = 0; j < 8; ++j) { short hi, lo; split_bf16(xv[i + j], hi, lo); vh[j] = hi; vl[j] = lo; }
      *(s8v*)&xhi[bb][uu * (KX / 16) + i] = vh;
      *(s8v*)&xlo[bb][uu * (KX / 16) + i] = vl;
    }
    __syncthreads();

    // ---- bf16x3 MFMA: 3 independent accumulator chains (hi*hi, lo*hi, hi*lo) ----
    f4v a0 = {0.f, 0.f, 0.f, 0.f}, a1 = a0, a2 = a0;
    #pragma unroll
    for (int kf = 0; kf < NKX; ++kf) {
      s8v ah = *(const s8v*)&xhi[n][kf * 32 + q * 8];  // A-frag: m=lane&15, k=q*8+j
      s8v al = *(const s8v*)&xlo[n][kf * 32 + q * 8];
      a0 = mfma16x16x32(ah, wxh[kf], a0);
      a1 = mfma16x16x32(al, wxh[kf], a1);
      a2 = mfma16x16x32(ah, wxl[kf], a2);
    }
    #pragma unroll
    for (int kf = 0; kf < 8; ++kf) {
      s8v ah = *(const s8v*)&hhi[n][kf * 32 + q * 8];
      s8v al = *(const s8v*)&hlo[n][kf * 32 + q * 8];
      a0 = mfma16x16x32(ah, whhh[kf], a0);
      a1 = mfma16x16x32(al, whhh[kf], a1);
      a2 = mfma16x16x32(ah, whhl[kf], a2);
    }
    f4v D = a0 + (a1 + a2);
    #pragma unroll
    for (int r = 0; r < 4; ++r) gl[w][q * 4 + r][n] = D[r];  // D: row m=q*4+r, col n=lane&15
    __syncthreads();

    // ---- activations + state update (one thread per (batch,unit)) ----
    float pi = gl[0][bb][uu] + bias_s[uu];
    float pf = gl[1][bb][uu] + bias_s[16 + uu];
    float pg = gl[2][bb][uu] + bias_s[32 + uu];
    float po = gl[3][bb][uu] + bias_s[48 + uu];
    float ig = sig_(pi), fg = sig_(pf), gg = th_(pg), og = sig_(po);
    c = fg * c + ig * gg;
    float h = og * th_(c);

    if (WRITE_SEQ) {
      seq_out[((size_t)(B0 + bb) * T_ + t) * H_ + U0 + uu] = h;
    } else if (t == T_ - 1) {
      seq_out[(B0 + bb) * H_ + U0 + uu] = h;
    }
    {
      unsigned* hbw = hb_base + ((unsigned)(t & 1)) * 4096u;
      __hip_atomic_store(&hbw[bb * 256 + U0 + uu], pack_hilo(h),
                         __ATOMIC_RELAXED, __HIP_MEMORY_SCOPE_AGENT);
    }
    __syncthreads();  // compiler drains vmcnt(0) before s_barrier -> all stores device-visible
    if (tid == 0)
      __hip_atomic_fetch_add(&cnt_g[t], 1u, __ATOMIC_RELEASE, __HIP_MEMORY_SCOPE_AGENT);
  }
}

__global__ void fc_kernel(const float* __restrict__ h1l, const float* __restrict__ Wfc,
                          float* __restrict__ out) {
  __shared__ float hs[H_];
  const int b = blockIdx.x, o = threadIdx.x;
  hs[o]       = h1l[b * H_ + o];
  hs[o + 128] = h1l[b * H_ + o + 128];
  __syncthreads();
  float acc = 0.f;
  #pragma unroll 8
  for (int u = 0; u < H_; u += 4) {
    float4 wv = *(const float4*)&Wfc[o * H_ + u];
    acc += wv.x * hs[u] + wv.y * hs[u + 1] + wv.z * hs[u + 2] + wv.w * hs[u + 3];
  }
  out[b * OUTD + o] = acc;
}

extern "C" void kernel_launch(void* const* d_in, const int* in_sizes, int n_in,
                              void* d_out, int out_size, void* d_ws, size_t ws_size,
                              hipStream_t stream) {
  const float* x    = (const float*)d_in[0];
  const float* Wih0 = (const float*)d_in[1];
  const float* Whh0 = (const float*)d_in[2];
  const float* bih0 = (const float*)d_in[3];
  const float* bhh0 = (const float*)d_in[4];
  const float* Wih1 = (const float*)d_in[5];
  const float* Whh1 = (const float*)d_in[6];
  const float* bih1 = (const float*)d_in[7];
  const float* bhh1 = (const float*)d_in[8];
  const float* Wfc  = (const float*)d_in[9];

  // ws layout (floats/uints): h0seq | hbuf | cnt0 | cnt1 | h1last  (~129 MiB total)
  float*    h0seq = (float*)d_ws;                  // 256*512*256
  unsigned* hbuf  = (unsigned*)(h0seq + 33554432); // 16*2*4096
  unsigned* cnt0  = hbuf + 131072;                 // 16*512
  unsigned* cnt1  = cnt0 + 8192;                   // 16*512
  float*    h1l   = (float*)(cnt1 + 8192);         // 256*256

  hipMemsetAsync(cnt0, 0, 2 * 8192 * sizeof(unsigned), stream);

  lstm_layer<128, true ><<<256, 256, 0, stream>>>(x,     Wih0, Whh0, bih0, bhh0, h0seq, hbuf, cnt0, n_in);
  lstm_layer<256, false><<<256, 256, 0, stream>>>(h0seq, Wih1, Whh1, bih1, bhh1, h1l,   hbuf, cnt1, n_in);
  fc_kernel<<<256, 128, 0, stream>>>(h1l, Wfc, (float*)d_out);
}

// Round 2
// 2709.143 us; speedup vs baseline: 4.6379x; 4.6379x over previous
//
#include <hip/hip_runtime.h>
#include <stdint.h>

#define T_   512
#define H_   256
#define OUTD 128

typedef unsigned long long u64;
typedef __attribute__((ext_vector_type(8))) short s8v;
typedef __attribute__((ext_vector_type(4))) float f4v;

__device__ __forceinline__ f4v mfma16x16x32(s8v a, s8v b, f4v c) {
  return __builtin_amdgcn_mfma_f32_16x16x32_bf16(a, b, c, 0, 0, 0);
}

// fp32 -> bf16 hi (truncate) + bf16 lo (RN of remainder)
__device__ __forceinline__ void split_bf16(float f, short &hi, short &lo) {
  unsigned u  = __float_as_uint(f);
  unsigned uh = u & 0xffff0000u;
  hi = (short)(uh >> 16);
  float r = f - __uint_as_float(uh);
  unsigned ur = __float_as_uint(r);
  lo = (short)((ur + 0x7fffu + ((ur >> 16) & 1u)) >> 16);
}

__device__ __forceinline__ unsigned pack_hilo(float f) {
  short hi, lo; split_bf16(f, hi, lo);
  return ((unsigned)(unsigned short)hi << 16) | (unsigned)(unsigned short)lo;
}

__device__ __forceinline__ float sig_(float x) { return 1.f / (1.f + __expf(-x)); }
__device__ __forceinline__ float th_(float x)  { float e = __expf(2.f * x); return 1.f - 2.f / (e + 1.f); }

struct SMem {
  short xhi[16][264], xlo[16][264];
  short hhi[16][264], hlo[16][264];
  float gl[4][16][17];
  float bias[64];
};  // 38400 B

// Exchange protocol: entry = u64 (tag<<32 | bf16hi<<16 | bf16lo), tag = step+1.
// Double-buffered by step parity. Tag-equality spin on exactly the data each
// thread consumes (8B atomicity => tag/data consistent; no fences, no RMW).
// Cross-layer back-pressure: layer1 members publish rflag=s+1 (plain store)
// after loading layer0 step-s data; layer0 waits rflag>=s-1 before overwriting.
template <int LAYER>
__device__ __forceinline__ void lstm_body(
    SMem* sm,
    const float* __restrict__ xin,
    const float* __restrict__ Wih, const float* __restrict__ Whh,
    const float* __restrict__ bih, const float* __restrict__ bhh,
    u64* bx_x,        // LAYER==1: consumed exchange (layer0 h)
    u64* bx_own,      // produced exchange (own h recurrence; layer0: also layer1's x)
    unsigned* rflag,  // [16 groups][16 members], stride 16 dwords
    float* h1l,       // LAYER==1: last h out [256,256]
    int g, int mem)
{
  constexpr int KX  = (LAYER == 0) ? 128 : 256;
  constexpr int NKX = KX / 32;
  const int tid = threadIdx.x;
  const int w = tid >> 6, lane = tid & 63, n = lane & 15, q = lane >> 4;
  const int bb = tid >> 4, uu = tid & 15;
  const int B0 = g * 16, U0 = mem * 16;

  // ---- weight slice -> register B-fragments (bf16 hi/lo), once ----
  s8v wxh[NKX], wxl[NKX], whhh[8], whhl[8];
  {
    const int row = w * 256 + U0 + n;
    #pragma unroll
    for (int kf = 0; kf < NKX; ++kf) {
      s8v vh, vl;
      #pragma unroll
      for (int j = 0; j < 8; ++j) { short hi, lo; split_bf16(Wih[row * KX + kf * 32 + q * 8 + j], hi, lo); vh[j] = hi; vl[j] = lo; }
      wxh[kf] = vh; wxl[kf] = vl;
    }
    #pragma unroll
    for (int kf = 0; kf < 8; ++kf) {
      s8v vh, vl;
      #pragma unroll
      for (int j = 0; j < 8; ++j) { short hi, lo; split_bf16(Whh[row * 256 + kf * 32 + q * 8 + j], hi, lo); vh[j] = hi; vl[j] = lo; }
      whhh[kf] = vh; whhl[kf] = vl;
    }
  }
  if (tid < 64) {
    int gate = tid >> 4, u = tid & 15;
    int grow = gate * 256 + U0 + u;
    sm->bias[tid] = bih[grow] + bhh[grow];
  }

  u64* own = bx_own + (size_t)g * 2 * 4096;
  u64* src = (LAYER == 1) ? (bx_x + (size_t)g * 2 * 4096) : nullptr;
  unsigned* rfg    = rflag + g * 256;       // member m's flag at rfg[m*16]
  unsigned* rfself = rfg + mem * 16;

  float c = 0.f;

  for (int s = 0; s < T_; ++s) {
    // ---- layer0: fp32 x prefetch (issued early, overlaps spins) ----
    float xv[8];
    if (LAYER == 0) {
      const float* px = xin + ((size_t)(B0 + bb) * T_ + s) * 128 + uu * 8;
      float4 v0 = *(const float4*)px, v1 = *(const float4*)(px + 4);
      xv[0] = v0.x; xv[1] = v0.y; xv[2] = v0.z; xv[3] = v0.w;
      xv[4] = v1.x; xv[5] = v1.y; xv[6] = v1.z; xv[7] = v1.w;
    }

    // ---- layer1: spin-consume layer0's step-s h (= our x) ----
    if (LAYER == 1) {
      const u64* pbx = src + (size_t)(s & 1) * 4096;
      const unsigned xtag = (unsigned)(s + 1);
      u64 xv64[16]; int it = 0;
      for (;;) {
        bool ok = true;
        #pragma unroll
        for (int i = 0; i < 16; ++i)
          xv64[i] = __hip_atomic_load(&pbx[i * 256 + tid], __ATOMIC_RELAXED, __HIP_MEMORY_SCOPE_AGENT);
        #pragma unroll
        for (int i = 0; i < 16; ++i) ok &= ((unsigned)(xv64[i] >> 32) == xtag);
        if (ok) break;
        if (++it >= 50000) break;          // no-hang safety
        __builtin_amdgcn_s_sleep(1);
      }
      #pragma unroll
      for (int i = 0; i < 16; ++i) {
        unsigned d = (unsigned)xv64[i];
        sm->xhi[i][tid] = (short)(d >> 16);
        sm->xlo[i][tid] = (short)(d & 0xffffu);
      }
    }

    // ---- spin-consume own group's h_{s-1} ----
    if (s > 0) {
      const u64* pbh = own + (size_t)((s - 1) & 1) * 4096;
      const unsigned htag = (unsigned)s;
      u64 hv64[16]; int it = 0;
      for (;;) {
        bool ok = true;
        #pragma unroll
        for (int i = 0; i < 16; ++i)
          hv64[i] = __hip_atomic_load(&pbh[i * 256 + tid], __ATOMIC_RELAXED, __HIP_MEMORY_SCOPE_AGENT);
        #pragma unroll
        for (int i = 0; i < 16; ++i) ok &= ((unsigned)(hv64[i] >> 32) == htag);
        if (ok) break;
        if (++it >= 50000) break;
        __builtin_amdgcn_s_sleep(1);
      }
      #pragma unroll
      for (int i = 0; i < 16; ++i) {
        unsigned d = (unsigned)hv64[i];
        sm->hhi[i][tid] = (short)(d >> 16);
        sm->hlo[i][tid] = (short)(d & 0xffffu);
      }
    } else {
      #pragma unroll
      for (int i = 0; i < 16; ++i) { sm->hhi[i][tid] = 0; sm->hlo[i][tid] = 0; }
    }

    // ---- layer0: stage fp32 x as bf16 hi/lo ----
    if (LAYER == 0) {
      s8v vh, vl;
      #pragma unroll
      for (int j = 0; j < 8; ++j) { short hi, lo; split_bf16(xv[j], hi, lo); vh[j] = hi; vl[j] = lo; }
      *(s8v*)&sm->xhi[bb][uu * 8] = vh;
      *(s8v*)&sm->xlo[bb][uu * 8] = vl;
    }
    __syncthreads();

    // layer1: publish read-progress (all threads' loads completed at barrier)
    if (LAYER == 1 && tid == 0)
      __hip_atomic_store(rfself, (unsigned)(s + 1), __ATOMIC_RELAXED, __HIP_MEMORY_SCOPE_AGENT);

    // ---- bf16x3 MFMA: hi*hi + lo*hi + hi*lo chains ----
    f4v a0 = {0.f, 0.f, 0.f, 0.f}, a1 = a0, a2 = a0;
    #pragma unroll
    for (int kf = 0; kf < NKX; ++kf) {
      s8v ah = *(const s8v*)&sm->xhi[n][kf * 32 + q * 8];
      s8v al = *(const s8v*)&sm->xlo[n][kf * 32 + q * 8];
      a0 = mfma16x16x32(ah, wxh[kf], a0);
      a1 = mfma16x16x32(al, wxh[kf], a1);
      a2 = mfma16x16x32(ah, wxl[kf], a2);
    }
    #pragma unroll
    for (int kf = 0; kf < 8; ++kf) {
      s8v ah = *(const s8v*)&sm->hhi[n][kf * 32 + q * 8];
      s8v al = *(const s8v*)&sm->hlo[n][kf * 32 + q * 8];
      a0 = mfma16x16x32(ah, whhh[kf], a0);
      a1 = mfma16x16x32(al, whhh[kf], a1);
      a2 = mfma16x16x32(ah, whhl[kf], a2);
    }
    f4v D = a0 + (a1 + a2);
    #pragma unroll
    for (int r = 0; r < 4; ++r) sm->gl[w][q * 4 + r][n] = D[r];
    __syncthreads();

    // ---- activations + state ----
    float pi = sm->gl[0][bb][uu] + sm->bias[uu];
    float pf = sm->gl[1][bb][uu] + sm->bias[16 + uu];
    float pg = sm->gl[2][bb][uu] + sm->bias[32 + uu];
    float po = sm->gl[3][bb][uu] + sm->bias[48 + uu];
    float ig = sig_(pi), fg = sig_(pf), gg = th_(pg), og = sig_(po);
    c = fg * c + ig * gg;
    float h = og * th_(c);

    // ---- layer0: back-pressure before overwriting slot (s&1) ----
    if (LAYER == 0) {
      if (s >= 2 && w == 0) {
        const unsigned tgt = (unsigned)(s - 1); int it = 0;
        for (;;) {
          unsigned v = (lane < 16)
            ? __hip_atomic_load(&rfg[lane * 16], __ATOMIC_RELAXED, __HIP_MEMORY_SCOPE_AGENT)
            : tgt;
          if (__all((int)(v >= tgt))) break;
          if (++it >= 50000) break;
          __builtin_amdgcn_s_sleep(1);
        }
      }
      __syncthreads();
    }

    // ---- publish h (tagged, fire-and-forget) ----
    u64 val = ((u64)(unsigned)(s + 1) << 32) | (u64)pack_hilo(h);
    __hip_atomic_store(&own[(size_t)(s & 1) * 4096 + bb * 256 + U0 + uu], val,
                       __ATOMIC_RELAXED, __HIP_MEMORY_SCOPE_AGENT);

    if (LAYER == 1 && s == T_ - 1)
      h1l[(B0 + bb) * H_ + U0 + uu] = h;
  }
}

__global__ __launch_bounds__(256, 2) void lstm_fused(
    const float* __restrict__ x,
    const float* __restrict__ Wih0, const float* __restrict__ Whh0,
    const float* __restrict__ bih0, const float* __restrict__ bhh0,
    const float* __restrict__ Wih1, const float* __restrict__ Whh1,
    const float* __restrict__ bih1, const float* __restrict__ bhh1,
    u64* bx0, u64* bx1, unsigned* rflag, float* h1l)
{
  __shared__ SMem sm;
  const int bid = blockIdx.x;
  if (bid < 256) {
    lstm_body<0>(&sm, x, Wih0, Whh0, bih0, bhh0, nullptr, bx0, rflag, nullptr,
                 bid >> 4, bid & 15);
  } else {
    const int b = bid - 256;
    lstm_body<1>(&sm, nullptr, Wih1, Whh1, bih1, bhh1, bx0, bx1, rflag, h1l,
                 b >> 4, b & 15);
  }
}

__global__ void fc_kernel(const float* __restrict__ h1l, const float* __restrict__ Wfc,
                          float* __restrict__ out) {
  __shared__ float hs[H_];
  const int b = blockIdx.x, o = threadIdx.x;
  hs[o]       = h1l[b * H_ + o];
  hs[o + 128] = h1l[b * H_ + o + 128];
  __syncthreads();
  float acc = 0.f;
  #pragma unroll 8
  for (int u = 0; u < H_; u += 4) {
    float4 wv = *(const float4*)&Wfc[o * H_ + u];
    acc += wv.x * hs[u] + wv.y * hs[u + 1] + wv.z * hs[u + 2] + wv.w * hs[u + 3];
  }
  out[b * OUTD + o] = acc;
}

extern "C" void kernel_launch(void* const* d_in, const int* in_sizes, int n_in,
                              void* d_out, int out_size, void* d_ws, size_t ws_size,
                              hipStream_t stream) {
  const float* x    = (const float*)d_in[0];
  const float* Wih0 = (const float*)d_in[1];
  const float* Whh0 = (const float*)d_in[2];
  const float* bih0 = (const float*)d_in[3];
  const float* bhh0 = (const float*)d_in[4];
  const float* Wih1 = (const float*)d_in[5];
  const float* Whh1 = (const float*)d_in[6];
  const float* bih1 = (const float*)d_in[7];
  const float* bhh1 = (const float*)d_in[8];
  const float* Wfc  = (const float*)d_in[9];

  // ws layout: bx0 (1 MiB) | bx1 (1 MiB) | rflag (16 KiB) | h1l (256 KiB)
  u64*      bx0   = (u64*)d_ws;            // 16*2*4096
  u64*      bx1   = bx0 + 131072;          // 16*2*4096
  unsigned* rflag = (unsigned*)(bx1 + 131072);  // 16*16*16
  float*    h1l   = (float*)(rflag + 4096);     // 256*256

  // rflag must start at 0 (poison 0xAA.. would spoof the >= back-pressure check;
  // exchange tags use equality so poison can never match them).
  hipMemsetAsync(rflag, 0, 4096 * sizeof(unsigned), stream);

  lstm_fused<<<512, 256, 0, stream>>>(x, Wih0, Whh0, bih0, bhh0,
                                      Wih1, Whh1, bih1, bhh1,
                                      bx0, bx1, rflag, h1l);
  fc_kernel<<<256, 128, 0, stream>>>(h1l, Wfc, (float*)d_out);
}